// Round 3
// baseline (3263.888 us; speedup 1.0000x reference)
//
#include <hip/hip_runtime.h>
#include <math.h>

#define B_T   128
#define NS    128
#define NQ    512
#define DIN   256
#define DOUT  64

#define MU_SIZE  (B_T*NQ*DOUT)            // 4,194,304 floats
#define SIG_SIZE (B_T*NQ*DOUT*DOUT)       // 268,435,456 floats
#define NLL_IDX  (MU_SIZE + SIG_SIZE)     // 272,629,760

// ---------------------------------------------------------------------------
// K0a: Sp = A @ A^T  (fp64 accumulate), alpha = 1
// ---------------------------------------------------------------------------
__global__ __launch_bounds__(256) void k_prior_sp(const float* __restrict__ A,
                                                  double* __restrict__ Sp) {
    __shared__ float Ai[16][260];
    __shared__ float Aj[16][260];
    int bi = blockIdx.x;
    int i0 = (bi >> 4) << 4;
    int j0 = (bi & 15) << 4;
    int tid = threadIdx.x;
    for (int idx = tid; idx < 16 * 256; idx += 256) {
        int r = idx >> 8, c = idx & 255;
        Ai[r][c] = A[(i0 + r) * 256 + c];
        Aj[r][c] = A[(j0 + r) * 256 + c];
    }
    __syncthreads();
    int r = tid >> 4, c = tid & 15;
    double acc = 0.0;
    for (int k = 0; k < 256; ++k)
        acc += (double)Ai[r][k] * (double)Aj[c][k];
    Sp[(i0 + r) * 256 + (j0 + c)] = acc;
}

// ---------------------------------------------------------------------------
// K0b: MPN = Sp @ m_prior
// ---------------------------------------------------------------------------
__global__ __launch_bounds__(64) void k_prior_mpn(const double* __restrict__ Sp,
                                                  const float* __restrict__ MP,
                                                  double* __restrict__ MPN) {
    int i = blockIdx.x, k = threadIdx.x;
    double acc = 0.0;
    for (int t = 0; t < 256; ++t)
        acc += Sp[i * 256 + t] * (double)MP[t * 64 + k];
    MPN[i * 64 + k] = acc;
}

// ---------------------------------------------------------------------------
// K1: G_b = Phi_s^T Phi_s + Sp   (lower-triangle 64x64 tiles only, fp64)
// ---------------------------------------------------------------------------
__global__ __launch_bounds__(256) void k_build_G(const float* __restrict__ PHI,
                                                 const double* __restrict__ Sp,
                                                 double* __restrict__ G) {
    __shared__ float As[128][64];
    __shared__ float Bs[128][64];
    int b = blockIdx.x;
    int by = blockIdx.y;
    int ti = 0;
    while (((ti + 1) * (ti + 2)) / 2 <= by) ti++;
    int tj = by - (ti * (ti + 1)) / 2;
    int i0 = ti * 64, j0 = tj * 64;
    int tid = threadIdx.x;
    const float* Pb = PHI + b * (NS * DIN);
    for (int idx = tid; idx < 128 * 64; idx += 256) {
        int n = idx >> 6, c = idx & 63;
        As[n][c] = Pb[n * 256 + i0 + c];
        Bs[n][c] = Pb[n * 256 + j0 + c];
    }
    __syncthreads();
    int tx = tid & 15, ty = tid >> 4;
    double acc[4][4];
#pragma unroll
    for (int r = 0; r < 4; ++r)
#pragma unroll
        for (int s = 0; s < 4; ++s) acc[r][s] = 0.0;
    for (int n = 0; n < 128; ++n) {
        float a0 = As[n][4 * ty + 0], a1 = As[n][4 * ty + 1];
        float a2 = As[n][4 * ty + 2], a3 = As[n][4 * ty + 3];
        float b0 = Bs[n][4 * tx + 0], b1 = Bs[n][4 * tx + 1];
        float b2 = Bs[n][4 * tx + 2], b3 = Bs[n][4 * tx + 3];
        acc[0][0] += (double)a0 * b0; acc[0][1] += (double)a0 * b1;
        acc[0][2] += (double)a0 * b2; acc[0][3] += (double)a0 * b3;
        acc[1][0] += (double)a1 * b0; acc[1][1] += (double)a1 * b1;
        acc[1][2] += (double)a1 * b2; acc[1][3] += (double)a1 * b3;
        acc[2][0] += (double)a2 * b0; acc[2][1] += (double)a2 * b1;
        acc[2][2] += (double)a2 * b2; acc[2][3] += (double)a2 * b3;
        acc[3][0] += (double)a3 * b0; acc[3][1] += (double)a3 * b1;
        acc[3][2] += (double)a3 * b2; acc[3][3] += (double)a3 * b3;
    }
    double* Gb = G + b * 65536;
#pragma unroll
    for (int r = 0; r < 4; ++r) {
        int i = i0 + 4 * ty + r;
#pragma unroll
        for (int s = 0; s < 4; ++s) {
            int j = j0 + 4 * tx + s;
            Gb[i * 256 + j] = acc[r][s] + Sp[i * 256 + j];
        }
    }
}

// ---------------------------------------------------------------------------
// K2: RHS_b = Phi_s^T Y_s + MPN  (fp64)
// ---------------------------------------------------------------------------
__global__ __launch_bounds__(256) void k_build_rhs(const float* __restrict__ PHI,
                                                   const float* __restrict__ Y,
                                                   const double* __restrict__ MPN,
                                                   double* __restrict__ RHS) {
    __shared__ float As[128][64];
    __shared__ float Ys[128][64];
    int b = blockIdx.x, i0 = blockIdx.y * 64, tid = threadIdx.x;
    const float* Pb = PHI + b * (NS * DIN);
    const float* Yb = Y + b * (NS * DOUT);
    for (int idx = tid; idx < 128 * 64; idx += 256) {
        int n = idx >> 6, c = idx & 63;
        As[n][c] = Pb[n * 256 + i0 + c];
        Ys[n][c] = Yb[n * 64 + c];
    }
    __syncthreads();
    int tx = tid & 15, ty = tid >> 4;
    double acc[4][4];
#pragma unroll
    for (int r = 0; r < 4; ++r)
#pragma unroll
        for (int s = 0; s < 4; ++s) acc[r][s] = 0.0;
    for (int n = 0; n < 128; ++n) {
        float a0 = As[n][4 * ty + 0], a1 = As[n][4 * ty + 1];
        float a2 = As[n][4 * ty + 2], a3 = As[n][4 * ty + 3];
        float y0 = Ys[n][4 * tx + 0], y1 = Ys[n][4 * tx + 1];
        float y2 = Ys[n][4 * tx + 2], y3 = Ys[n][4 * tx + 3];
        acc[0][0] += (double)a0 * y0; acc[0][1] += (double)a0 * y1;
        acc[0][2] += (double)a0 * y2; acc[0][3] += (double)a0 * y3;
        acc[1][0] += (double)a1 * y0; acc[1][1] += (double)a1 * y1;
        acc[1][2] += (double)a1 * y2; acc[1][3] += (double)a1 * y3;
        acc[2][0] += (double)a2 * y0; acc[2][1] += (double)a2 * y1;
        acc[2][2] += (double)a2 * y2; acc[2][3] += (double)a2 * y3;
        acc[3][0] += (double)a3 * y0; acc[3][1] += (double)a3 * y1;
        acc[3][2] += (double)a3 * y2; acc[3][3] += (double)a3 * y3;
    }
    double* Rb = RHS + b * 16384;
#pragma unroll
    for (int r = 0; r < 4; ++r) {
        int i = i0 + 4 * ty + r;
#pragma unroll
        for (int s = 0; s < 4; ++s) {
            int kc = 4 * tx + s;
            Rb[i * 64 + kc] = acc[r][s] + MPN[i * 64 + kc];
        }
    }
}

// ---------------------------------------------------------------------------
// K3: blocked Cholesky, NB=32 (fp64). Panel in 64 KB LDS with (row+p)&255
//     swizzle (all accesses <=2-way bank aliasing = free). Diag 32x32 block
//     factored wave-synchronously in registers by wave 0 (shfl broadcasts,
//     zero barriers); other rows do an independent 32-step row-solve.
//     4 barriers per panel (was 64). Writes LT[k*256+i] = L[i][k] (i>=k).
// ---------------------------------------------------------------------------
#define PP(p, row) P[p][((row) + (p)) & 255]

__global__ __launch_bounds__(256) void k_chol(double* __restrict__ G,
                                              double* __restrict__ LT) {
    __shared__ double P[32][256];    // 64 KB, swizzled columns of the panel
    __shared__ double dinvs[32];
    int b = blockIdx.x, tid = threadIdx.x;
    double* Gb = G + b * 65536;
    double* LTb = LT + b * 65536;
    for (int k0 = 0; k0 < 256; k0 += 32) {
        int rows = 256 - k0;
        // stage panel: global read coalesced (256 B row segments),
        // LDS write stride 257 doubles -> 2-way (free)
        for (int idx = tid; idx < rows * 32; idx += 256) {
            int r = k0 + (idx >> 5), p = idx & 31;
            PP(p, r) = Gb[r * 256 + k0 + p];
        }
        __syncthreads();
        // wave 0: register Cholesky of the 32x32 diagonal block (lane = row)
        if (tid < 32) {
            double x[32];
#pragma unroll
            for (int p = 0; p < 32; ++p) x[p] = PP(p, k0 + tid);
            for (int p = 0; p < 32; ++p) {
                double dpp = __shfl(x[p], p);
                double d = sqrt(fmax(dpp, 1e-300));
                double inv = 1.0 / d;
                if (tid == p) { x[p] = d; dinvs[p] = inv; }
                else if (tid > p) x[p] *= inv;
                for (int p2 = p + 1; p2 < 32; ++p2) {
                    double lp2 = __shfl(x[p], p2);   // L[k0+p2][k0+p]
                    if (tid >= p2) x[p2] -= x[p] * lp2;
                }
            }
#pragma unroll
            for (int p = 0; p < 32; ++p) PP(p, k0 + tid) = x[p];
        }
        __syncthreads();
        // independent row-solve: L[i][k0+p] for rows i >= k0+32
        if (tid >= k0 + 32) {
            int i = tid;
            double xr[32];
#pragma unroll
            for (int p = 0; p < 32; ++p) {
                double v = PP(p, i);
                for (int p2 = 0; p2 < p; ++p2)
                    v -= xr[p2] * PP(p2, k0 + p);    // broadcast
                xr[p] = v * dinvs[p];
            }
#pragma unroll
            for (int p = 0; p < 32; ++p) PP(p, i) = xr[p];
        }
        __syncthreads();
        // write finished panel to LT (coalesced rows)
        for (int p = 0; p < 32; ++p) {
            int r = k0 + p + tid;
            if (r < 256) LTb[(k0 + p) * 256 + r] = PP(p, r);
        }
        // trailing update: 1 row x 2 cols per thread, 32-deep register panel
        int ty = tid >> 4, tx = tid & 15;
        for (int i = k0 + 32 + ty; i < 256; i += 16) {
            double pi[32];
#pragma unroll
            for (int p = 0; p < 32; ++p) pi[p] = PP(p, i);
            for (int jg = k0 + 32; jg <= i; jg += 32) {
                int j = jg + 2 * tx;
                double g0 = Gb[i * 256 + j];
                double g1 = Gb[i * 256 + j + 1];
#pragma unroll
                for (int p = 0; p < 32; ++p) {
                    g0 -= pi[p] * PP(p, j);
                    g1 -= pi[p] * PP(p, j + 1);
                }
                if (j <= i) Gb[i * 256 + j] = g0;
                if (j + 1 <= i) Gb[i * 256 + j + 1] = g1;
            }
        }
        __syncthreads();
    }
}

// ---------------------------------------------------------------------------
// K3b: blocked triangular inversion  Tinv = L^{-1}  (fp64), per-task block.
//      Writes TI[i*256+k] (full square, zeros above diag) and fp32 copy TIF.
// ---------------------------------------------------------------------------
__global__ __launch_bounds__(256) void k_trinv(const double* __restrict__ LT,
                                               double* __restrict__ TI,
                                               float* __restrict__ TIF) {
    __shared__ double SHD[8192];   // 64 KB: 8 diag blocks, SHD[g*1024+k*32+i]=L[32g+i][32g+k]
    int b = blockIdx.x, tid = threadIdx.x;
    const double* LTb = LT + b * 65536;
    double* TIb = TI + b * 65536;
    float* TIFb = TIF + b * 65536;
    for (int idx = tid; idx < 65536; idx += 256) {
        int i = idx >> 8, k = idx & 255;
        if (k > i) { TIb[idx] = 0.0; TIFb[idx] = 0.0f; }
    }
    for (int idx = tid; idx < 8192; idx += 256) {
        int g = idx >> 10, rem = idx & 1023, k = rem >> 5, i = rem & 31;
        SHD[idx] = LTb[(32 * g + k) * 256 + 32 * g + i];
    }
    __syncthreads();
    {
        int g = tid >> 5, j = tid & 31;
        const double* D = SHD + g * 1024;       // D[k*32+i] = L[i][k]
        double x[32];
#pragma unroll
        for (int i = 0; i < 32; ++i) {
            double s = (i == j) ? 1.0 : 0.0;
#pragma unroll
            for (int k = 0; k < i; ++k) {
                double lv = D[k * 32 + i];
                s -= (k >= j) ? lv * x[k] : 0.0;
            }
            double inv = 1.0 / D[i * 32 + i];
            x[i] = (i >= j) ? s * inv : 0.0;
        }
#pragma unroll
        for (int i = 0; i < 32; ++i) {
            int gi = 32 * g + i, gj = 32 * g + j;
            TIb[gi * 256 + gj] = x[i];
            TIFb[gi * 256 + gj] = (float)x[i];
        }
    }
    __syncthreads();
    double* Bsh = SHD;
    int j = tid & 31, ig = tid >> 5;
    for (int I = 1; I < 8; ++I) {
        for (int J = I - 1; J >= 0; --J) {
            double acc[4] = {0.0, 0.0, 0.0, 0.0};
            for (int K = J; K < I; ++K) {
                for (int kk = 0; kk < 32; ++kk) {
                    double tv = TIb[(32 * K + kk) * 256 + 32 * J + j];
#pragma unroll
                    for (int r = 0; r < 4; ++r) {
                        double lv = LTb[(32 * K + kk) * 256 + 32 * I + ig * 4 + r];
                        acc[r] += lv * tv;
                    }
                }
            }
            __syncthreads();
#pragma unroll
            for (int r = 0; r < 4; ++r) Bsh[(ig * 4 + r) * 32 + j] = acc[r];
            __syncthreads();
            double c[4] = {0.0, 0.0, 0.0, 0.0};
            for (int k = 0; k < 32; ++k) {
                double bv = Bsh[k * 32 + j];
#pragma unroll
                for (int r = 0; r < 4; ++r) {
                    double dv = TIb[(32 * I + ig * 4 + r) * 256 + 32 * I + k];
                    c[r] -= dv * bv;
                }
            }
#pragma unroll
            for (int r = 0; r < 4; ++r) {
                int gi = 32 * I + ig * 4 + r, gj = 32 * J + j;
                TIb[gi * 256 + gj] = c[r];
                TIFb[gi * 256 + gj] = (float)c[r];
            }
        }
        __syncthreads();
    }
}

// ---------------------------------------------------------------------------
// K4a: Z = Tinv @ RHS  (fp64 tiled GEMM, triangular k-skip)
// ---------------------------------------------------------------------------
__global__ __launch_bounds__(256) void k_gemm_Z(const double* __restrict__ TI,
                                                const double* __restrict__ RHS,
                                                double* __restrict__ Z) {
    __shared__ double As[32][64];
    __shared__ double Bs[64][64];
    int b = blockIdx.x, i0 = blockIdx.y * 32;
    int tid = threadIdx.x, c = tid & 63, rg = tid >> 6;
    const double* TIb = TI + b * 65536;
    const double* Rb = RHS + b * 16384;
    double* Zb = Z + b * 16384;
    double acc[8] = {};
    for (int k0 = 0; k0 <= i0; k0 += 64) {
        for (int idx = tid; idx < 2048; idx += 256) {
            int r = idx >> 6, kk = idx & 63;
            As[r][kk] = TIb[(i0 + r) * 256 + k0 + kk];
        }
        for (int idx = tid; idx < 4096; idx += 256) {
            int kk = idx >> 6, cc = idx & 63;
            Bs[kk][cc] = Rb[(k0 + kk) * 64 + cc];
        }
        __syncthreads();
        for (int kk = 0; kk < 64; ++kk) {
            double bv = Bs[kk][c];
#pragma unroll
            for (int r = 0; r < 8; ++r)
                acc[r] += As[rg * 8 + r][kk] * bv;
        }
        __syncthreads();
    }
#pragma unroll
    for (int r = 0; r < 8; ++r)
        Zb[(i0 + rg * 8 + r) * 64 + c] = acc[r];
}

// ---------------------------------------------------------------------------
// K4b: M = Tinv^T @ Z  (fp64 tiled GEMM, triangular k-skip), M -> RHS buffer
// ---------------------------------------------------------------------------
__global__ __launch_bounds__(256) void k_gemm_M(const double* __restrict__ TI,
                                                const double* __restrict__ Z,
                                                double* __restrict__ M) {
    __shared__ double As[64][32];
    __shared__ double Bs[64][64];
    int b = blockIdx.x, i0 = blockIdx.y * 32;
    int tid = threadIdx.x, c = tid & 63, rg = tid >> 6;
    const double* TIb = TI + b * 65536;
    const double* Zb = Z + b * 16384;
    double* Mb = M + b * 16384;
    double acc[8] = {};
    for (int k0 = (i0 >> 6) << 6; k0 < 256; k0 += 64) {
        for (int idx = tid; idx < 2048; idx += 256) {
            int kk = idx >> 5, ri = idx & 31;
            As[kk][ri] = TIb[(k0 + kk) * 256 + i0 + ri];
        }
        for (int idx = tid; idx < 4096; idx += 256) {
            int kk = idx >> 6, cc = idx & 63;
            Bs[kk][cc] = Zb[(k0 + kk) * 64 + cc];
        }
        __syncthreads();
        for (int kk = 0; kk < 64; ++kk) {
            double bv = Bs[kk][c];
#pragma unroll
            for (int r = 0; r < 8; ++r)
                acc[r] += As[kk][rg * 8 + r] * bv;
        }
        __syncthreads();
    }
#pragma unroll
    for (int r = 0; r < 8; ++r)
        Mb[(i0 + rg * 8 + r) * 64 + c] = acc[r];
}

// ---------------------------------------------------------------------------
// K5a: W = PhiQ @ TinvF^T, PSUM[b][I][q] = sum_{i in I-tile} W[q][i]^2 (fp32)
//      LDS tiles in [k][x] layout -> float4 (ds_read_b128) operand loads.
// ---------------------------------------------------------------------------
__global__ __launch_bounds__(256) void k_spread_gemm(const float* __restrict__ PHIQ,
                                                     const float* __restrict__ TIF,
                                                     float* __restrict__ PSUM) {
    __shared__ float Qs[64][68];   // [k][q]
    __shared__ float Ts[64][68];   // [k][i]
    int b = blockIdx.x, q0 = blockIdx.y * 64, I = blockIdx.z, i0 = I * 64;
    int tid = threadIdx.x, tx = tid & 15, ty = tid >> 4;
    const float* Qb = PHIQ + b * (NQ * DIN) + q0 * DIN;
    const float* Tb = TIF + b * 65536;
    float acc[4][4];
#pragma unroll
    for (int r = 0; r < 4; ++r)
#pragma unroll
        for (int s = 0; s < 4; ++s) acc[r][s] = 0.0f;
    for (int k0 = 0; k0 <= i0; k0 += 64) {
        for (int idx = tid; idx < 4096; idx += 256) {
            int r = idx >> 6, c = idx & 63;
            Qs[c][r] = Qb[r * 256 + k0 + c];
            Ts[c][r] = Tb[(i0 + r) * 256 + k0 + c];
        }
        __syncthreads();
        for (int kk = 0; kk < 64; ++kk) {
            float4 a = *(const float4*)&Qs[kk][4 * ty];
            float4 bb = *(const float4*)&Ts[kk][4 * tx];
            acc[0][0] += a.x * bb.x; acc[0][1] += a.x * bb.y; acc[0][2] += a.x * bb.z; acc[0][3] += a.x * bb.w;
            acc[1][0] += a.y * bb.x; acc[1][1] += a.y * bb.y; acc[1][2] += a.y * bb.z; acc[1][3] += a.y * bb.w;
            acc[2][0] += a.z * bb.x; acc[2][1] += a.z * bb.y; acc[2][2] += a.z * bb.z; acc[2][3] += a.z * bb.w;
            acc[3][0] += a.w * bb.x; acc[3][1] += a.w * bb.y; acc[3][2] += a.w * bb.z; acc[3][3] += a.w * bb.w;
        }
        __syncthreads();
    }
#pragma unroll
    for (int r = 0; r < 4; ++r) {
        float p = acc[r][0] * acc[r][0] + acc[r][1] * acc[r][1]
                + acc[r][2] * acc[r][2] + acc[r][3] * acc[r][3];
        p += __shfl_down(p, 8, 16);
        p += __shfl_down(p, 4, 16);
        p += __shfl_down(p, 2, 16);
        p += __shfl_down(p, 1, 16);
        if (tx == 0) PSUM[(size_t)(b * 4 + I) * 512 + q0 + 4 * ty + r] = p;
    }
}

// ---------------------------------------------------------------------------
// K5b: SPREAD = 1 + sum_I PSUM
// ---------------------------------------------------------------------------
__global__ __launch_bounds__(256) void k_spread_combine(const float* __restrict__ PSUM,
                                                        float* __restrict__ SPREAD) {
    int b = blockIdx.x;
    for (int q = threadIdx.x; q < 512; q += 256) {
        float s = 1.0f;
#pragma unroll
        for (int I = 0; I < 4; ++I) s += PSUM[(size_t)(b * 4 + I) * 512 + q];
        SPREAD[b * 512 + q] = s;
    }
}

// ---------------------------------------------------------------------------
// K6: mu = Phi_q @ m  (fp32 GEMM, m cast from fp64), float4 operand loads
// ---------------------------------------------------------------------------
__global__ __launch_bounds__(256) void k_mu(const float* __restrict__ PHIQ,
                                            const double* __restrict__ M,
                                            float* __restrict__ MU) {
    __shared__ float Qs[64][68];   // [k][q]
    __shared__ float Ms[64][64];   // [k][c]
    int b = blockIdx.x, q0 = blockIdx.y * 64, tid = threadIdx.x;
    int tx = tid & 15, ty = tid >> 4;
    const float* Qb = PHIQ + b * (NQ * DIN) + q0 * DIN;
    const double* Mb = M + b * 16384;
    float acc[4][4];
#pragma unroll
    for (int r = 0; r < 4; ++r)
#pragma unroll
        for (int s = 0; s < 4; ++s) acc[r][s] = 0.0f;
    for (int c0 = 0; c0 < 256; c0 += 64) {
        for (int idx = tid; idx < 4096; idx += 256) {
            int r = idx >> 6, c = idx & 63;
            Qs[c][r] = Qb[r * 256 + c0 + c];
            Ms[r][c] = (float)Mb[(c0 + r) * 64 + c];
        }
        __syncthreads();
        for (int kk = 0; kk < 64; ++kk) {
            float4 a = *(const float4*)&Qs[kk][4 * ty];
            float4 bb = *(const float4*)&Ms[kk][4 * tx];
            acc[0][0] += a.x * bb.x; acc[0][1] += a.x * bb.y; acc[0][2] += a.x * bb.z; acc[0][3] += a.x * bb.w;
            acc[1][0] += a.y * bb.x; acc[1][1] += a.y * bb.y; acc[1][2] += a.y * bb.z; acc[1][3] += a.y * bb.w;
            acc[2][0] += a.z * bb.x; acc[2][1] += a.z * bb.y; acc[2][2] += a.z * bb.z; acc[2][3] += a.z * bb.w;
            acc[3][0] += a.w * bb.x; acc[3][1] += a.w * bb.y; acc[3][2] += a.w * bb.z; acc[3][3] += a.w * bb.w;
        }
        __syncthreads();
    }
#pragma unroll
    for (int r = 0; r < 4; ++r) {
        float4 v = make_float4(acc[r][0], acc[r][1], acc[r][2], acc[r][3]);
        *(float4*)&MU[(b * NQ + q0 + 4 * ty + r) * 64 + 4 * tx] = v;
    }
}

// ---------------------------------------------------------------------------
// K8: nll partial sums
// ---------------------------------------------------------------------------
__global__ __launch_bounds__(256) void k_nll_part(const float* __restrict__ YQ,
                                                  const float* __restrict__ MU,
                                                  const float* __restrict__ SPREAD,
                                                  const float* __restrict__ SE,
                                                  double* __restrict__ NLLP) {
    __shared__ double red[256];
    int tid = threadIdx.x;
    int bq = blockIdx.x * 256 + tid;
    float se = SE[0];
    float sp = SPREAD[bq];
    float qs = 0.0f;
    const float4* y4 = (const float4*)(YQ + bq * 64);
    const float4* m4 = (const float4*)(MU + bq * 64);
#pragma unroll
    for (int t = 0; t < 16; ++t) {
        float4 y = y4[t], m = m4[t];
        float dx = y.x - m.x, dy = y.y - m.y, dz = y.z - m.z, dw = y.w - m.w;
        qs += dx * dx + dy * dy + dz * dz + dw * dw;
    }
    float val = 64.0f * (logf(sp) + logf(se)) + qs / (sp * se);
    red[tid] = (double)val;
    __syncthreads();
    for (int s = 128; s > 0; s >>= 1) {
        if (tid < s) red[tid] += red[tid + s];
        __syncthreads();
    }
    if (tid == 0) NLLP[blockIdx.x] = red[0] * (1.0 / 65536.0);
}

__global__ __launch_bounds__(256) void k_nll_final(const double* __restrict__ NLLP,
                                                   float* __restrict__ out) {
    __shared__ double red[256];
    int tid = threadIdx.x;
    red[tid] = NLLP[tid];
    __syncthreads();
    for (int s = 128; s > 0; s >>= 1) {
        if (tid < s) red[tid] += red[tid + s];
        __syncthreads();
    }
    if (tid == 0) out[NLL_IDX] = (float)red[0];
}

// ---------------------------------------------------------------------------
// K7 (runs LAST): stream sig; fully overwrites scratch inside d_out sig region.
// ---------------------------------------------------------------------------
__global__ __launch_bounds__(256) void k_sig(const float* __restrict__ SPREAD,
                                             const float* __restrict__ SE,
                                             float* __restrict__ out) {
    __shared__ float sv_s;
    int bq = blockIdx.x, tid = threadIdx.x;
    if (tid == 0) sv_s = SPREAD[bq] * SE[0];
    __syncthreads();
    float sv = sv_s;
    float* base = out + (size_t)MU_SIZE + (size_t)bq * 4096;
    int i = tid >> 2;
    int jb = (tid & 3) << 4;
    int d = i - jb;
    float vals[16];
#pragma unroll
    for (int t = 0; t < 16; ++t) vals[t] = (t == d) ? sv : 0.0f;
    float4* p = (float4*)(base + tid * 16);
    p[0] = make_float4(vals[0], vals[1], vals[2], vals[3]);
    p[1] = make_float4(vals[4], vals[5], vals[6], vals[7]);
    p[2] = make_float4(vals[8], vals[9], vals[10], vals[11]);
    p[3] = make_float4(vals[12], vals[13], vals[14], vals[15]);
}

// ---------------------------------------------------------------------------
extern "C" void kernel_launch(void* const* d_in, const int* in_sizes, int n_in,
                              void* d_out, int out_size, void* d_ws, size_t ws_size,
                              hipStream_t stream) {
    const float* PHI_S = (const float*)d_in[0];
    const float* Y_S   = (const float*)d_in[1];
    const float* PHI_Q = (const float*)d_in[2];
    const float* Y_Q   = (const float*)d_in[3];
    const float* MP    = (const float*)d_in[4];
    const float* AP    = (const float*)d_in[5];
    const float* SE    = (const float*)d_in[6];
    float* out = (float*)d_out;

    // Big scratch inside sig region of d_out (dead before k_sig runs last).
    double* scratch = (double*)(out + MU_SIZE);
    double* G    = scratch;                    // 8,388,608 dbl (64 MB)
    double* LT   = G + 8388608;                // 8,388,608 dbl
    double* RHS  = LT + 8388608;               // 2,097,152 dbl (-> becomes M)
    double* Z    = RHS + 2097152;              // 2,097,152 dbl
    double* TI   = Z + 2097152;                // 8,388,608 dbl
    double* Spd  = TI + 8388608;               // 65,536 dbl
    double* MPN  = Spd + 65536;                // 16,384 dbl
    float*  TIF  = (float*)(MPN + 16384);      // 8,388,608 f32 (32 MB)
    float*  PSUM = TIF + 8388608;              // 262,144 f32 (1 MB)
    // Small persistent scratch (survives until k_sig) in d_ws.
    float*  SPREAD = (float*)d_ws;                       // 65,536 f32
    double* NLLP   = (double*)((char*)d_ws + 65536 * 4); // 256 dbl

    k_prior_sp      <<<256, 256, 0, stream>>>(AP, Spd);
    k_prior_mpn     <<<256, 64, 0, stream>>>(Spd, MP, MPN);
    k_build_G       <<<dim3(B_T, 10), 256, 0, stream>>>(PHI_S, Spd, G);
    k_build_rhs     <<<dim3(B_T, 4), 256, 0, stream>>>(PHI_S, Y_S, MPN, RHS);
    k_chol          <<<B_T, 256, 0, stream>>>(G, LT);
    k_trinv         <<<B_T, 256, 0, stream>>>(LT, TI, TIF);
    k_gemm_Z        <<<dim3(B_T, 8), 256, 0, stream>>>(TI, RHS, Z);
    k_gemm_M        <<<dim3(B_T, 8), 256, 0, stream>>>(TI, Z, RHS);
    k_spread_gemm   <<<dim3(B_T, 8, 4), 256, 0, stream>>>(PHI_Q, TIF, PSUM);
    k_spread_combine<<<B_T, 256, 0, stream>>>(PSUM, SPREAD);
    k_mu            <<<dim3(B_T, 8), 256, 0, stream>>>(PHI_Q, RHS, out);
    k_nll_part      <<<256, 256, 0, stream>>>(Y_Q, out, SPREAD, SE, NLLP);
    k_nll_final     <<<1, 256, 0, stream>>>(NLLP, out);
    k_sig           <<<65536, 256, 0, stream>>>(SPREAD, SE, out);   // LAST
}

// Round 4
// 3160.893 us; speedup vs baseline: 1.0326x; 1.0326x over previous
//
#include <hip/hip_runtime.h>
#include <math.h>

#define B_T   128
#define NS    128
#define NQ    512
#define DIN   256
#define DOUT  64

#define MU_SIZE  (B_T*NQ*DOUT)            // 4,194,304 floats
#define SIG_SIZE (B_T*NQ*DOUT*DOUT)       // 268,435,456 floats
#define NLL_IDX  (MU_SIZE + SIG_SIZE)     // 272,629,760

// ---------------------------------------------------------------------------
// K0a: Sp = A @ A^T  (fp64 accumulate), alpha = 1
// ---------------------------------------------------------------------------
__global__ __launch_bounds__(256) void k_prior_sp(const float* __restrict__ A,
                                                  double* __restrict__ Sp) {
    __shared__ float Ai[16][260];
    __shared__ float Aj[16][260];
    int bi = blockIdx.x;
    int i0 = (bi >> 4) << 4;
    int j0 = (bi & 15) << 4;
    int tid = threadIdx.x;
    for (int idx = tid; idx < 16 * 256; idx += 256) {
        int r = idx >> 8, c = idx & 255;
        Ai[r][c] = A[(i0 + r) * 256 + c];
        Aj[r][c] = A[(j0 + r) * 256 + c];
    }
    __syncthreads();
    int r = tid >> 4, c = tid & 15;
    double acc = 0.0;
    for (int k = 0; k < 256; ++k)
        acc += (double)Ai[r][k] * (double)Aj[c][k];
    Sp[(i0 + r) * 256 + (j0 + c)] = acc;
}

// ---------------------------------------------------------------------------
// K0b: MPN = Sp @ m_prior
// ---------------------------------------------------------------------------
__global__ __launch_bounds__(64) void k_prior_mpn(const double* __restrict__ Sp,
                                                  const float* __restrict__ MP,
                                                  double* __restrict__ MPN) {
    int i = blockIdx.x, k = threadIdx.x;
    double acc = 0.0;
    for (int t = 0; t < 256; ++t)
        acc += Sp[i * 256 + t] * (double)MP[t * 64 + k];
    MPN[i * 64 + k] = acc;
}

// ---------------------------------------------------------------------------
// K1: G_b = Phi_s^T Phi_s + Sp   (lower-triangle 64x64 tiles only, fp64)
// ---------------------------------------------------------------------------
__global__ __launch_bounds__(256) void k_build_G(const float* __restrict__ PHI,
                                                 const double* __restrict__ Sp,
                                                 double* __restrict__ G) {
    __shared__ float As[128][64];
    __shared__ float Bs[128][64];
    int b = blockIdx.x;
    int by = blockIdx.y;
    int ti = 0;
    while (((ti + 1) * (ti + 2)) / 2 <= by) ti++;
    int tj = by - (ti * (ti + 1)) / 2;
    int i0 = ti * 64, j0 = tj * 64;
    int tid = threadIdx.x;
    const float* Pb = PHI + b * (NS * DIN);
    for (int idx = tid; idx < 128 * 64; idx += 256) {
        int n = idx >> 6, c = idx & 63;
        As[n][c] = Pb[n * 256 + i0 + c];
        Bs[n][c] = Pb[n * 256 + j0 + c];
    }
    __syncthreads();
    int tx = tid & 15, ty = tid >> 4;
    double acc[4][4];
#pragma unroll
    for (int r = 0; r < 4; ++r)
#pragma unroll
        for (int s = 0; s < 4; ++s) acc[r][s] = 0.0;
    for (int n = 0; n < 128; ++n) {
        float a0 = As[n][4 * ty + 0], a1 = As[n][4 * ty + 1];
        float a2 = As[n][4 * ty + 2], a3 = As[n][4 * ty + 3];
        float b0 = Bs[n][4 * tx + 0], b1 = Bs[n][4 * tx + 1];
        float b2 = Bs[n][4 * tx + 2], b3 = Bs[n][4 * tx + 3];
        acc[0][0] += (double)a0 * b0; acc[0][1] += (double)a0 * b1;
        acc[0][2] += (double)a0 * b2; acc[0][3] += (double)a0 * b3;
        acc[1][0] += (double)a1 * b0; acc[1][1] += (double)a1 * b1;
        acc[1][2] += (double)a1 * b2; acc[1][3] += (double)a1 * b3;
        acc[2][0] += (double)a2 * b0; acc[2][1] += (double)a2 * b1;
        acc[2][2] += (double)a2 * b2; acc[2][3] += (double)a2 * b3;
        acc[3][0] += (double)a3 * b0; acc[3][1] += (double)a3 * b1;
        acc[3][2] += (double)a3 * b2; acc[3][3] += (double)a3 * b3;
    }
    double* Gb = G + b * 65536;
#pragma unroll
    for (int r = 0; r < 4; ++r) {
        int i = i0 + 4 * ty + r;
#pragma unroll
        for (int s = 0; s < 4; ++s) {
            int j = j0 + 4 * tx + s;
            Gb[i * 256 + j] = acc[r][s] + Sp[i * 256 + j];
        }
    }
}

// ---------------------------------------------------------------------------
// K2: RHS_b = Phi_s^T Y_s + MPN  (fp64)
// ---------------------------------------------------------------------------
__global__ __launch_bounds__(256) void k_build_rhs(const float* __restrict__ PHI,
                                                   const float* __restrict__ Y,
                                                   const double* __restrict__ MPN,
                                                   double* __restrict__ RHS) {
    __shared__ float As[128][64];
    __shared__ float Ys[128][64];
    int b = blockIdx.x, i0 = blockIdx.y * 64, tid = threadIdx.x;
    const float* Pb = PHI + b * (NS * DIN);
    const float* Yb = Y + b * (NS * DOUT);
    for (int idx = tid; idx < 128 * 64; idx += 256) {
        int n = idx >> 6, c = idx & 63;
        As[n][c] = Pb[n * 256 + i0 + c];
        Ys[n][c] = Yb[n * 64 + c];
    }
    __syncthreads();
    int tx = tid & 15, ty = tid >> 4;
    double acc[4][4];
#pragma unroll
    for (int r = 0; r < 4; ++r)
#pragma unroll
        for (int s = 0; s < 4; ++s) acc[r][s] = 0.0;
    for (int n = 0; n < 128; ++n) {
        float a0 = As[n][4 * ty + 0], a1 = As[n][4 * ty + 1];
        float a2 = As[n][4 * ty + 2], a3 = As[n][4 * ty + 3];
        float y0 = Ys[n][4 * tx + 0], y1 = Ys[n][4 * tx + 1];
        float y2 = Ys[n][4 * tx + 2], y3 = Ys[n][4 * tx + 3];
        acc[0][0] += (double)a0 * y0; acc[0][1] += (double)a0 * y1;
        acc[0][2] += (double)a0 * y2; acc[0][3] += (double)a0 * y3;
        acc[1][0] += (double)a1 * y0; acc[1][1] += (double)a1 * y1;
        acc[1][2] += (double)a1 * y2; acc[1][3] += (double)a1 * y3;
        acc[2][0] += (double)a2 * y0; acc[2][1] += (double)a2 * y1;
        acc[2][2] += (double)a2 * y2; acc[2][3] += (double)a2 * y3;
        acc[3][0] += (double)a3 * y0; acc[3][1] += (double)a3 * y1;
        acc[3][2] += (double)a3 * y2; acc[3][3] += (double)a3 * y3;
    }
    double* Rb = RHS + b * 16384;
#pragma unroll
    for (int r = 0; r < 4; ++r) {
        int i = i0 + 4 * ty + r;
#pragma unroll
        for (int s = 0; s < 4; ++s) {
            int kc = 4 * tx + s;
            Rb[i * 64 + kc] = acc[r][s] + MPN[i * 64 + kc];
        }
    }
}

// ---------------------------------------------------------------------------
// K3a: panel factor for right-looking blocked Cholesky, NB=32.
//      Stages G[k0:256, k0:k0+32] in LDS ((row+p)&255 swizzle), factors the
//      32x32 diag wave-synchronously in wave 0 (shfl), then independent
//      per-thread row-solves. Writes LT[k*256+i] = L[i][k].
// ---------------------------------------------------------------------------
#define PP(p, row) P[p][((row) + (p)) & 255]

__global__ __launch_bounds__(256) void k_panel(const double* __restrict__ G,
                                               double* __restrict__ LT,
                                               int k0) {
    __shared__ double P[32][256];
    __shared__ double dinvs[32];
    int b = blockIdx.x, tid = threadIdx.x;
    const double* Gb = G + b * 65536;
    double* LTb = LT + b * 65536;
    int rows = 256 - k0;
    for (int idx = tid; idx < rows * 32; idx += 256) {
        int r = k0 + (idx >> 5), p = idx & 31;
        PP(p, r) = Gb[r * 256 + k0 + p];
    }
    __syncthreads();
    // wave 0: register Cholesky of the 32x32 diagonal block (lane = row)
    if (tid < 32) {
        double x[32];
#pragma unroll
        for (int p = 0; p < 32; ++p) x[p] = PP(p, k0 + tid);
        for (int p = 0; p < 32; ++p) {
            double dpp = __shfl(x[p], p);
            double d = sqrt(fmax(dpp, 1e-300));
            double inv = 1.0 / d;
            if (tid == p) { x[p] = d; dinvs[p] = inv; }
            else if (tid > p) x[p] *= inv;
            for (int p2 = p + 1; p2 < 32; ++p2) {
                double lp2 = __shfl(x[p], p2);   // L[k0+p2][k0+p]
                if (tid >= p2) x[p2] -= x[p] * lp2;
            }
        }
#pragma unroll
        for (int p = 0; p < 32; ++p) PP(p, k0 + tid) = x[p];
    }
    __syncthreads();
    // independent row-solve for rows i >= k0+32 (one row per thread)
    if (tid >= k0 + 32) {
        int i = tid;
        double xr[32];
#pragma unroll
        for (int p = 0; p < 32; ++p) {
            double v = PP(p, i);
            for (int p2 = 0; p2 < p; ++p2)
                v -= xr[p2] * PP(p2, k0 + p);    // broadcast reads
            xr[p] = v * dinvs[p];
        }
#pragma unroll
        for (int p = 0; p < 32; ++p) PP(p, i) = xr[p];
    }
    __syncthreads();
    // write finished panel to LT (coalesced rows)
    for (int p = 0; p < 32; ++p) {
        int r = k0 + p + tid;
        if (r < 256) LTb[(k0 + p) * 256 + r] = PP(p, r);
    }
}

// ---------------------------------------------------------------------------
// K3b: trailing SYRK update, one 32x32 tile per block (massively parallel):
//      G[i][j] -= sum_p L[i][k0+p]*L[j][k0+p] for i,j in [k0+32, 256), j<=i.
// ---------------------------------------------------------------------------
__global__ __launch_bounds__(256) void k_trail(double* __restrict__ G,
                                               const double* __restrict__ LT,
                                               int k0) {
    __shared__ double Li[32][34];
    __shared__ double Lj[32][34];
    int b = blockIdx.x, t = blockIdx.y, tid = threadIdx.x;
    int ti = 0;
    while (((ti + 1) * (ti + 2)) / 2 <= t) ti++;
    int tj = t - (ti * (ti + 1)) / 2;
    int i0 = k0 + 32 + ti * 32, j0 = k0 + 32 + tj * 32;
    const double* LTb = LT + b * 65536;
    double* Gb = G + b * 65536;
    for (int idx = tid; idx < 1024; idx += 256) {
        int p = idx >> 5, ii = idx & 31;
        Li[p][ii] = LTb[(k0 + p) * 256 + i0 + ii];
        Lj[p][ii] = LTb[(k0 + p) * 256 + j0 + ii];
    }
    __syncthreads();
    int ty = tid >> 4, tx = tid & 15;
    double a00 = 0.0, a01 = 0.0, a10 = 0.0, a11 = 0.0;
#pragma unroll
    for (int p = 0; p < 32; ++p) {
        double l0 = Li[p][2 * ty], l1 = Li[p][2 * ty + 1];
        double r0 = Lj[p][2 * tx], r1 = Lj[p][2 * tx + 1];
        a00 += l0 * r0; a01 += l0 * r1;
        a10 += l1 * r0; a11 += l1 * r1;
    }
    int gi0 = i0 + 2 * ty, gj0 = j0 + 2 * tx;
    if (gj0 <= gi0)     Gb[gi0 * 256 + gj0]           -= a00;
    if (gj0 + 1 <= gi0) Gb[gi0 * 256 + gj0 + 1]       -= a01;
    if (gj0 <= gi0 + 1) Gb[(gi0 + 1) * 256 + gj0]     -= a10;
    if (gj0 + 1 <= gi0 + 1) Gb[(gi0 + 1) * 256 + gj0 + 1] -= a11;
}

// ---------------------------------------------------------------------------
// K3c: blocked triangular inversion  Tinv = L^{-1}  (fp64), per-task block.
//      Writes TI[i*256+k] (full square, zeros above diag) and fp32 copy TIF.
// ---------------------------------------------------------------------------
__global__ __launch_bounds__(256) void k_trinv(const double* __restrict__ LT,
                                               double* __restrict__ TI,
                                               float* __restrict__ TIF) {
    __shared__ double SHD[8192];   // 64 KB: 8 diag blocks, SHD[g*1024+k*32+i]=L[32g+i][32g+k]
    int b = blockIdx.x, tid = threadIdx.x;
    const double* LTb = LT + b * 65536;
    double* TIb = TI + b * 65536;
    float* TIFb = TIF + b * 65536;
    for (int idx = tid; idx < 65536; idx += 256) {
        int i = idx >> 8, k = idx & 255;
        if (k > i) { TIb[idx] = 0.0; TIFb[idx] = 0.0f; }
    }
    for (int idx = tid; idx < 8192; idx += 256) {
        int g = idx >> 10, rem = idx & 1023, k = rem >> 5, i = rem & 31;
        SHD[idx] = LTb[(32 * g + k) * 256 + 32 * g + i];
    }
    __syncthreads();
    {
        int g = tid >> 5, j = tid & 31;
        const double* D = SHD + g * 1024;       // D[k*32+i] = L[i][k]
        double x[32];
#pragma unroll
        for (int i = 0; i < 32; ++i) {
            double s = (i == j) ? 1.0 : 0.0;
#pragma unroll
            for (int k = 0; k < i; ++k) {
                double lv = D[k * 32 + i];
                s -= (k >= j) ? lv * x[k] : 0.0;
            }
            double inv = 1.0 / D[i * 32 + i];
            x[i] = (i >= j) ? s * inv : 0.0;
        }
#pragma unroll
        for (int i = 0; i < 32; ++i) {
            int gi = 32 * g + i, gj = 32 * g + j;
            TIb[gi * 256 + gj] = x[i];
            TIFb[gi * 256 + gj] = (float)x[i];
        }
    }
    __syncthreads();
    double* Bsh = SHD;
    int j = tid & 31, ig = tid >> 5;
    for (int I = 1; I < 8; ++I) {
        for (int J = I - 1; J >= 0; --J) {
            double acc[4] = {0.0, 0.0, 0.0, 0.0};
            for (int K = J; K < I; ++K) {
                for (int kk = 0; kk < 32; ++kk) {
                    double tv = TIb[(32 * K + kk) * 256 + 32 * J + j];
#pragma unroll
                    for (int r = 0; r < 4; ++r) {
                        double lv = LTb[(32 * K + kk) * 256 + 32 * I + ig * 4 + r];
                        acc[r] += lv * tv;
                    }
                }
            }
            __syncthreads();
#pragma unroll
            for (int r = 0; r < 4; ++r) Bsh[(ig * 4 + r) * 32 + j] = acc[r];
            __syncthreads();
            double c[4] = {0.0, 0.0, 0.0, 0.0};
            for (int k = 0; k < 32; ++k) {
                double bv = Bsh[k * 32 + j];
#pragma unroll
                for (int r = 0; r < 4; ++r) {
                    double dv = TIb[(32 * I + ig * 4 + r) * 256 + 32 * I + k];
                    c[r] -= dv * bv;
                }
            }
#pragma unroll
            for (int r = 0; r < 4; ++r) {
                int gi = 32 * I + ig * 4 + r, gj = 32 * J + j;
                TIb[gi * 256 + gj] = c[r];
                TIFb[gi * 256 + gj] = (float)c[r];
            }
        }
        __syncthreads();
    }
}

// ---------------------------------------------------------------------------
// K4a: Z = Tinv @ RHS  (fp64 tiled GEMM, triangular k-skip)
// ---------------------------------------------------------------------------
__global__ __launch_bounds__(256) void k_gemm_Z(const double* __restrict__ TI,
                                                const double* __restrict__ RHS,
                                                double* __restrict__ Z) {
    __shared__ double As[32][64];
    __shared__ double Bs[64][64];
    int b = blockIdx.x, i0 = blockIdx.y * 32;
    int tid = threadIdx.x, c = tid & 63, rg = tid >> 6;
    const double* TIb = TI + b * 65536;
    const double* Rb = RHS + b * 16384;
    double* Zb = Z + b * 16384;
    double acc[8] = {};
    for (int k0 = 0; k0 <= i0; k0 += 64) {
        for (int idx = tid; idx < 2048; idx += 256) {
            int r = idx >> 6, kk = idx & 63;
            As[r][kk] = TIb[(i0 + r) * 256 + k0 + kk];
        }
        for (int idx = tid; idx < 4096; idx += 256) {
            int kk = idx >> 6, cc = idx & 63;
            Bs[kk][cc] = Rb[(k0 + kk) * 64 + cc];
        }
        __syncthreads();
        for (int kk = 0; kk < 64; ++kk) {
            double bv = Bs[kk][c];
#pragma unroll
            for (int r = 0; r < 8; ++r)
                acc[r] += As[rg * 8 + r][kk] * bv;
        }
        __syncthreads();
    }
#pragma unroll
    for (int r = 0; r < 8; ++r)
        Zb[(i0 + rg * 8 + r) * 64 + c] = acc[r];
}

// ---------------------------------------------------------------------------
// K4b: M = Tinv^T @ Z  (fp64 tiled GEMM, triangular k-skip), M -> RHS buffer
// ---------------------------------------------------------------------------
__global__ __launch_bounds__(256) void k_gemm_M(const double* __restrict__ TI,
                                                const double* __restrict__ Z,
                                                double* __restrict__ M) {
    __shared__ double As[64][32];
    __shared__ double Bs[64][64];
    int b = blockIdx.x, i0 = blockIdx.y * 32;
    int tid = threadIdx.x, c = tid & 63, rg = tid >> 6;
    const double* TIb = TI + b * 65536;
    const double* Zb = Z + b * 16384;
    double* Mb = M + b * 16384;
    double acc[8] = {};
    for (int k0 = (i0 >> 6) << 6; k0 < 256; k0 += 64) {
        for (int idx = tid; idx < 2048; idx += 256) {
            int kk = idx >> 5, ri = idx & 31;
            As[kk][ri] = TIb[(k0 + kk) * 256 + i0 + ri];
        }
        for (int idx = tid; idx < 4096; idx += 256) {
            int kk = idx >> 6, cc = idx & 63;
            Bs[kk][cc] = Zb[(k0 + kk) * 64 + cc];
        }
        __syncthreads();
        for (int kk = 0; kk < 64; ++kk) {
            double bv = Bs[kk][c];
#pragma unroll
            for (int r = 0; r < 8; ++r)
                acc[r] += As[kk][rg * 8 + r] * bv;
        }
        __syncthreads();
    }
#pragma unroll
    for (int r = 0; r < 8; ++r)
        Mb[(i0 + rg * 8 + r) * 64 + c] = acc[r];
}

// ---------------------------------------------------------------------------
// K5a: W = PhiQ @ TinvF^T, PSUM[b][I][q] = sum_{i in I-tile} W[q][i]^2 (fp32)
//      LDS tiles in [k][x] layout -> float4 (ds_read_b128) operand loads.
// ---------------------------------------------------------------------------
__global__ __launch_bounds__(256) void k_spread_gemm(const float* __restrict__ PHIQ,
                                                     const float* __restrict__ TIF,
                                                     float* __restrict__ PSUM) {
    __shared__ float Qs[64][68];   // [k][q]
    __shared__ float Ts[64][68];   // [k][i]
    int b = blockIdx.x, q0 = blockIdx.y * 64, I = blockIdx.z, i0 = I * 64;
    int tid = threadIdx.x, tx = tid & 15, ty = tid >> 4;
    const float* Qb = PHIQ + b * (NQ * DIN) + q0 * DIN;
    const float* Tb = TIF + b * 65536;
    float acc[4][4];
#pragma unroll
    for (int r = 0; r < 4; ++r)
#pragma unroll
        for (int s = 0; s < 4; ++s) acc[r][s] = 0.0f;
    for (int k0 = 0; k0 <= i0; k0 += 64) {
        for (int idx = tid; idx < 4096; idx += 256) {
            int r = idx >> 6, c = idx & 63;
            Qs[c][r] = Qb[r * 256 + k0 + c];
            Ts[c][r] = Tb[(i0 + r) * 256 + k0 + c];
        }
        __syncthreads();
        for (int kk = 0; kk < 64; ++kk) {
            float4 a = *(const float4*)&Qs[kk][4 * ty];
            float4 bb = *(const float4*)&Ts[kk][4 * tx];
            acc[0][0] += a.x * bb.x; acc[0][1] += a.x * bb.y; acc[0][2] += a.x * bb.z; acc[0][3] += a.x * bb.w;
            acc[1][0] += a.y * bb.x; acc[1][1] += a.y * bb.y; acc[1][2] += a.y * bb.z; acc[1][3] += a.y * bb.w;
            acc[2][0] += a.z * bb.x; acc[2][1] += a.z * bb.y; acc[2][2] += a.z * bb.z; acc[2][3] += a.z * bb.w;
            acc[3][0] += a.w * bb.x; acc[3][1] += a.w * bb.y; acc[3][2] += a.w * bb.z; acc[3][3] += a.w * bb.w;
        }
        __syncthreads();
    }
#pragma unroll
    for (int r = 0; r < 4; ++r) {
        float p = acc[r][0] * acc[r][0] + acc[r][1] * acc[r][1]
                + acc[r][2] * acc[r][2] + acc[r][3] * acc[r][3];
        p += __shfl_down(p, 8, 16);
        p += __shfl_down(p, 4, 16);
        p += __shfl_down(p, 2, 16);
        p += __shfl_down(p, 1, 16);
        if (tx == 0) PSUM[(size_t)(b * 4 + I) * 512 + q0 + 4 * ty + r] = p;
    }
}

// ---------------------------------------------------------------------------
// K5b: SPREAD = 1 + sum_I PSUM
// ---------------------------------------------------------------------------
__global__ __launch_bounds__(256) void k_spread_combine(const float* __restrict__ PSUM,
                                                        float* __restrict__ SPREAD) {
    int b = blockIdx.x;
    for (int q = threadIdx.x; q < 512; q += 256) {
        float s = 1.0f;
#pragma unroll
        for (int I = 0; I < 4; ++I) s += PSUM[(size_t)(b * 4 + I) * 512 + q];
        SPREAD[b * 512 + q] = s;
    }
}

// ---------------------------------------------------------------------------
// K6: mu = Phi_q @ m  (fp32 GEMM, m cast from fp64), float4 operand loads
// ---------------------------------------------------------------------------
__global__ __launch_bounds__(256) void k_mu(const float* __restrict__ PHIQ,
                                            const double* __restrict__ M,
                                            float* __restrict__ MU) {
    __shared__ float Qs[64][68];   // [k][q]
    __shared__ float Ms[64][64];   // [k][c]
    int b = blockIdx.x, q0 = blockIdx.y * 64, tid = threadIdx.x;
    int tx = tid & 15, ty = tid >> 4;
    const float* Qb = PHIQ + b * (NQ * DIN) + q0 * DIN;
    const double* Mb = M + b * 16384;
    float acc[4][4];
#pragma unroll
    for (int r = 0; r < 4; ++r)
#pragma unroll
        for (int s = 0; s < 4; ++s) acc[r][s] = 0.0f;
    for (int c0 = 0; c0 < 256; c0 += 64) {
        for (int idx = tid; idx < 4096; idx += 256) {
            int r = idx >> 6, c = idx & 63;
            Qs[c][r] = Qb[r * 256 + c0 + c];
            Ms[r][c] = (float)Mb[(c0 + r) * 64 + c];
        }
        __syncthreads();
        for (int kk = 0; kk < 64; ++kk) {
            float4 a = *(const float4*)&Qs[kk][4 * ty];
            float4 bb = *(const float4*)&Ms[kk][4 * tx];
            acc[0][0] += a.x * bb.x; acc[0][1] += a.x * bb.y; acc[0][2] += a.x * bb.z; acc[0][3] += a.x * bb.w;
            acc[1][0] += a.y * bb.x; acc[1][1] += a.y * bb.y; acc[1][2] += a.y * bb.z; acc[1][3] += a.y * bb.w;
            acc[2][0] += a.z * bb.x; acc[2][1] += a.z * bb.y; acc[2][2] += a.z * bb.z; acc[2][3] += a.z * bb.w;
            acc[3][0] += a.w * bb.x; acc[3][1] += a.w * bb.y; acc[3][2] += a.w * bb.z; acc[3][3] += a.w * bb.w;
        }
        __syncthreads();
    }
#pragma unroll
    for (int r = 0; r < 4; ++r) {
        float4 v = make_float4(acc[r][0], acc[r][1], acc[r][2], acc[r][3]);
        *(float4*)&MU[(b * NQ + q0 + 4 * ty + r) * 64 + 4 * tx] = v;
    }
}

// ---------------------------------------------------------------------------
// K8: nll partial sums
// ---------------------------------------------------------------------------
__global__ __launch_bounds__(256) void k_nll_part(const float* __restrict__ YQ,
                                                  const float* __restrict__ MU,
                                                  const float* __restrict__ SPREAD,
                                                  const float* __restrict__ SE,
                                                  double* __restrict__ NLLP) {
    __shared__ double red[256];
    int tid = threadIdx.x;
    int bq = blockIdx.x * 256 + tid;
    float se = SE[0];
    float sp = SPREAD[bq];
    float qs = 0.0f;
    const float4* y4 = (const float4*)(YQ + bq * 64);
    const float4* m4 = (const float4*)(MU + bq * 64);
#pragma unroll
    for (int t = 0; t < 16; ++t) {
        float4 y = y4[t], m = m4[t];
        float dx = y.x - m.x, dy = y.y - m.y, dz = y.z - m.z, dw = y.w - m.w;
        qs += dx * dx + dy * dy + dz * dz + dw * dw;
    }
    float val = 64.0f * (logf(sp) + logf(se)) + qs / (sp * se);
    red[tid] = (double)val;
    __syncthreads();
    for (int s = 128; s > 0; s >>= 1) {
        if (tid < s) red[tid] += red[tid + s];
        __syncthreads();
    }
    if (tid == 0) NLLP[blockIdx.x] = red[0] * (1.0 / 65536.0);
}

__global__ __launch_bounds__(256) void k_nll_final(const double* __restrict__ NLLP,
                                                   float* __restrict__ out) {
    __shared__ double red[256];
    int tid = threadIdx.x;
    red[tid] = NLLP[tid];
    __syncthreads();
    for (int s = 128; s > 0; s >>= 1) {
        if (tid < s) red[tid] += red[tid + s];
        __syncthreads();
    }
    if (tid == 0) out[NLL_IDX] = (float)red[0];
}

// ---------------------------------------------------------------------------
// K7 (runs LAST): stream sig; fully overwrites scratch inside d_out sig region.
// ---------------------------------------------------------------------------
__global__ __launch_bounds__(256) void k_sig(const float* __restrict__ SPREAD,
                                             const float* __restrict__ SE,
                                             float* __restrict__ out) {
    __shared__ float sv_s;
    int bq = blockIdx.x, tid = threadIdx.x;
    if (tid == 0) sv_s = SPREAD[bq] * SE[0];
    __syncthreads();
    float sv = sv_s;
    float* base = out + (size_t)MU_SIZE + (size_t)bq * 4096;
    int i = tid >> 2;
    int jb = (tid & 3) << 4;
    int d = i - jb;
    float vals[16];
#pragma unroll
    for (int t = 0; t < 16; ++t) vals[t] = (t == d) ? sv : 0.0f;
    float4* p = (float4*)(base + tid * 16);
    p[0] = make_float4(vals[0], vals[1], vals[2], vals[3]);
    p[1] = make_float4(vals[4], vals[5], vals[6], vals[7]);
    p[2] = make_float4(vals[8], vals[9], vals[10], vals[11]);
    p[3] = make_float4(vals[12], vals[13], vals[14], vals[15]);
}

// ---------------------------------------------------------------------------
extern "C" void kernel_launch(void* const* d_in, const int* in_sizes, int n_in,
                              void* d_out, int out_size, void* d_ws, size_t ws_size,
                              hipStream_t stream) {
    const float* PHI_S = (const float*)d_in[0];
    const float* Y_S   = (const float*)d_in[1];
    const float* PHI_Q = (const float*)d_in[2];
    const float* Y_Q   = (const float*)d_in[3];
    const float* MP    = (const float*)d_in[4];
    const float* AP    = (const float*)d_in[5];
    const float* SE    = (const float*)d_in[6];
    float* out = (float*)d_out;

    // Big scratch inside sig region of d_out (dead before k_sig runs last).
    double* scratch = (double*)(out + MU_SIZE);
    double* G    = scratch;                    // 8,388,608 dbl (64 MB)
    double* LT   = G + 8388608;                // 8,388,608 dbl
    double* RHS  = LT + 8388608;               // 2,097,152 dbl (-> becomes M)
    double* Z    = RHS + 2097152;              // 2,097,152 dbl
    double* TI   = Z + 2097152;                // 8,388,608 dbl
    double* Spd  = TI + 8388608;               // 65,536 dbl
    double* MPN  = Spd + 65536;                // 16,384 dbl
    float*  TIF  = (float*)(MPN + 16384);      // 8,388,608 f32 (32 MB)
    float*  PSUM = TIF + 8388608;              // 262,144 f32 (1 MB)
    // Small persistent scratch (survives until k_sig) in d_ws.
    float*  SPREAD = (float*)d_ws;                       // 65,536 f32
    double* NLLP   = (double*)((char*)d_ws + 65536 * 4); // 256 dbl

    k_prior_sp      <<<256, 256, 0, stream>>>(AP, Spd);
    k_prior_mpn     <<<256, 64, 0, stream>>>(Spd, MP, MPN);
    k_build_G       <<<dim3(B_T, 10), 256, 0, stream>>>(PHI_S, Spd, G);
    k_build_rhs     <<<dim3(B_T, 4), 256, 0, stream>>>(PHI_S, Y_S, MPN, RHS);
    // Blocked right-looking Cholesky: panel (low-parallelism, tiny) +
    // trailing SYRK (thousands of blocks) per 32-wide panel.
    for (int p = 0; p < 8; ++p) {
        int k0 = 32 * p;
        k_panel<<<B_T, 256, 0, stream>>>(G, LT, k0);
        int T = 7 - p;
        if (T > 0) {
            int ntiles = T * (T + 1) / 2;
            k_trail<<<dim3(B_T, ntiles), 256, 0, stream>>>(G, LT, k0);
        }
    }
    k_trinv         <<<B_T, 256, 0, stream>>>(LT, TI, TIF);
    k_gemm_Z        <<<dim3(B_T, 8), 256, 0, stream>>>(TI, RHS, Z);
    k_gemm_M        <<<dim3(B_T, 8), 256, 0, stream>>>(TI, Z, RHS);
    k_spread_gemm   <<<dim3(B_T, 8, 4), 256, 0, stream>>>(PHI_Q, TIF, PSUM);
    k_spread_combine<<<B_T, 256, 0, stream>>>(PSUM, SPREAD);
    k_mu            <<<dim3(B_T, 8), 256, 0, stream>>>(PHI_Q, RHS, out);
    k_nll_part      <<<256, 256, 0, stream>>>(Y_Q, out, SPREAD, SE, NLLP);
    k_nll_final     <<<1, 256, 0, stream>>>(NLLP, out);
    k_sig           <<<65536, 256, 0, stream>>>(SPREAD, SE, out);   // LAST
}

// Round 5
// 2244.464 us; speedup vs baseline: 1.4542x; 1.4083x over previous
//
#include <hip/hip_runtime.h>
#include <math.h>

#define B_T   128
#define NS    128
#define NQ    512
#define DIN   256
#define DOUT  64

#define MU_SIZE  (B_T*NQ*DOUT)            // 4,194,304 floats
#define SIG_SIZE (B_T*NQ*DOUT*DOUT)       // 268,435,456 floats
#define NLL_IDX  (MU_SIZE + SIG_SIZE)     // 272,629,760

// ---------------------------------------------------------------------------
// K0a: Sp = A @ A^T  (fp64 accumulate); also zeroes the NLL accumulator.
// ---------------------------------------------------------------------------
__global__ __launch_bounds__(256) void k_prior_sp(const float* __restrict__ A,
                                                  double* __restrict__ Sp,
                                                  double* __restrict__ NLLACC) {
    __shared__ float Ai[16][260];
    __shared__ float Aj[16][260];
    int bi = blockIdx.x;
    int i0 = (bi >> 4) << 4;
    int j0 = (bi & 15) << 4;
    int tid = threadIdx.x;
    if (bi == 0 && tid == 0) NLLACC[0] = 0.0;
    for (int idx = tid; idx < 16 * 256; idx += 256) {
        int r = idx >> 8, c = idx & 255;
        Ai[r][c] = A[(i0 + r) * 256 + c];
        Aj[r][c] = A[(j0 + r) * 256 + c];
    }
    __syncthreads();
    int r = tid >> 4, c = tid & 15;
    double acc = 0.0;
    for (int k = 0; k < 256; ++k)
        acc += (double)Ai[r][k] * (double)Aj[c][k];
    Sp[(i0 + r) * 256 + (j0 + c)] = acc;
}

// ---------------------------------------------------------------------------
// K0b: MPN = Sp @ m_prior
// ---------------------------------------------------------------------------
__global__ __launch_bounds__(64) void k_prior_mpn(const double* __restrict__ Sp,
                                                  const float* __restrict__ MP,
                                                  double* __restrict__ MPN) {
    int i = blockIdx.x, k = threadIdx.x;
    double acc = 0.0;
    for (int t = 0; t < 256; ++t)
        acc += Sp[i * 256 + t] * (double)MP[t * 64 + k];
    MPN[i * 64 + k] = acc;
}

// ---------------------------------------------------------------------------
// K1: G_b = Phi_s^T Phi_s + Sp   (lower-triangle 64x64 tiles only, fp64)
// ---------------------------------------------------------------------------
__global__ __launch_bounds__(256) void k_build_G(const float* __restrict__ PHI,
                                                 const double* __restrict__ Sp,
                                                 double* __restrict__ G) {
    __shared__ float As[128][64];
    __shared__ float Bs[128][64];
    int b = blockIdx.x;
    int by = blockIdx.y;
    int ti = 0;
    while (((ti + 1) * (ti + 2)) / 2 <= by) ti++;
    int tj = by - (ti * (ti + 1)) / 2;
    int i0 = ti * 64, j0 = tj * 64;
    int tid = threadIdx.x;
    const float* Pb = PHI + b * (NS * DIN);
    for (int idx = tid; idx < 128 * 64; idx += 256) {
        int n = idx >> 6, c = idx & 63;
        As[n][c] = Pb[n * 256 + i0 + c];
        Bs[n][c] = Pb[n * 256 + j0 + c];
    }
    __syncthreads();
    int tx = tid & 15, ty = tid >> 4;
    double acc[4][4];
#pragma unroll
    for (int r = 0; r < 4; ++r)
#pragma unroll
        for (int s = 0; s < 4; ++s) acc[r][s] = 0.0;
    for (int n = 0; n < 128; ++n) {
        float a0 = As[n][4 * ty + 0], a1 = As[n][4 * ty + 1];
        float a2 = As[n][4 * ty + 2], a3 = As[n][4 * ty + 3];
        float b0 = Bs[n][4 * tx + 0], b1 = Bs[n][4 * tx + 1];
        float b2 = Bs[n][4 * tx + 2], b3 = Bs[n][4 * tx + 3];
        acc[0][0] += (double)a0 * b0; acc[0][1] += (double)a0 * b1;
        acc[0][2] += (double)a0 * b2; acc[0][3] += (double)a0 * b3;
        acc[1][0] += (double)a1 * b0; acc[1][1] += (double)a1 * b1;
        acc[1][2] += (double)a1 * b2; acc[1][3] += (double)a1 * b3;
        acc[2][0] += (double)a2 * b0; acc[2][1] += (double)a2 * b1;
        acc[2][2] += (double)a2 * b2; acc[2][3] += (double)a2 * b3;
        acc[3][0] += (double)a3 * b0; acc[3][1] += (double)a3 * b1;
        acc[3][2] += (double)a3 * b2; acc[3][3] += (double)a3 * b3;
    }
    double* Gb = G + b * 65536;
#pragma unroll
    for (int r = 0; r < 4; ++r) {
        int i = i0 + 4 * ty + r;
#pragma unroll
        for (int s = 0; s < 4; ++s) {
            int j = j0 + 4 * tx + s;
            Gb[i * 256 + j] = acc[r][s] + Sp[i * 256 + j];
        }
    }
}

// ---------------------------------------------------------------------------
// K2: RHS_b = Phi_s^T Y_s + MPN  (fp64)
// ---------------------------------------------------------------------------
__global__ __launch_bounds__(256) void k_build_rhs(const float* __restrict__ PHI,
                                                   const float* __restrict__ Y,
                                                   const double* __restrict__ MPN,
                                                   double* __restrict__ RHS) {
    __shared__ float As[128][64];
    __shared__ float Ys[128][64];
    int b = blockIdx.x, i0 = blockIdx.y * 64, tid = threadIdx.x;
    const float* Pb = PHI + b * (NS * DIN);
    const float* Yb = Y + b * (NS * DOUT);
    for (int idx = tid; idx < 128 * 64; idx += 256) {
        int n = idx >> 6, c = idx & 63;
        As[n][c] = Pb[n * 256 + i0 + c];
        Ys[n][c] = Yb[n * 64 + c];
    }
    __syncthreads();
    int tx = tid & 15, ty = tid >> 4;
    double acc[4][4];
#pragma unroll
    for (int r = 0; r < 4; ++r)
#pragma unroll
        for (int s = 0; s < 4; ++s) acc[r][s] = 0.0;
    for (int n = 0; n < 128; ++n) {
        float a0 = As[n][4 * ty + 0], a1 = As[n][4 * ty + 1];
        float a2 = As[n][4 * ty + 2], a3 = As[n][4 * ty + 3];
        float y0 = Ys[n][4 * tx + 0], y1 = Ys[n][4 * tx + 1];
        float y2 = Ys[n][4 * tx + 2], y3 = Ys[n][4 * tx + 3];
        acc[0][0] += (double)a0 * y0; acc[0][1] += (double)a0 * y1;
        acc[0][2] += (double)a0 * y2; acc[0][3] += (double)a0 * y3;
        acc[1][0] += (double)a1 * y0; acc[1][1] += (double)a1 * y1;
        acc[1][2] += (double)a1 * y2; acc[1][3] += (double)a1 * y3;
        acc[2][0] += (double)a2 * y0; acc[2][1] += (double)a2 * y1;
        acc[2][2] += (double)a2 * y2; acc[2][3] += (double)a2 * y3;
        acc[3][0] += (double)a3 * y0; acc[3][1] += (double)a3 * y1;
        acc[3][2] += (double)a3 * y2; acc[3][3] += (double)a3 * y3;
    }
    double* Rb = RHS + b * 16384;
#pragma unroll
    for (int r = 0; r < 4; ++r) {
        int i = i0 + 4 * ty + r;
#pragma unroll
        for (int s = 0; s < 4; ++s) {
            int kc = 4 * tx + s;
            Rb[i * 64 + kc] = acc[r][s] + MPN[i * 64 + kc];
        }
    }
}

// ---------------------------------------------------------------------------
// K3: FUSED per-task Cholesky (NB=16, in-place on G, writes LT[k*256+i]) +
//     blocked triangular inversion Tinv = L^{-1} (TI fp64, TIF fp32).
//     One block per task; 64 KB LDS reused across phases.
// ---------------------------------------------------------------------------
__global__ __launch_bounds__(256) void k_cholinv(double* __restrict__ G,
                                                 double* __restrict__ LT,
                                                 double* __restrict__ TI,
                                                 float* __restrict__ TIF) {
    __shared__ double S[8192];          // 64 KB scratch, reused per phase
    int b = blockIdx.x, tid = threadIdx.x;
    double* Gb = G + b * 65536;
    double* LTb = LT + b * 65536;
    double* TIb = TI + b * 65536;
    float* TIFb = TIF + b * 65536;

    // ---------------- phase 1: blocked Cholesky, NB=16 ----------------
    double* P = S;                       // panel: 16 x 258 doubles (33 KB)
#define PCH(p, r) P[(p) * 258 + (r)]
    for (int k0 = 0; k0 < 256; k0 += 16) {
        int rows = 256 - k0;
        for (int idx = tid; idx < rows * 16; idx += 256) {
            int r = k0 + (idx >> 4), p = idx & 15;
            PCH(p, r) = Gb[r * 256 + k0 + p];
        }
        __syncthreads();
        for (int p = 0; p < 16; ++p) {
            int k = k0 + p;
            if (tid >= k) {
                double v = PCH(p, tid);
                for (int p2 = 0; p2 < p; ++p2) v -= PCH(p2, tid) * PCH(p2, k);
                PCH(p, tid) = v;
            }
            __syncthreads();
            double d = sqrt(fmax(PCH(p, k), 1e-300));
            double inv = 1.0 / d;
            if (tid > k) PCH(p, tid) *= inv;
            else if (tid == k) PCH(p, tid) = d;
            __syncthreads();
        }
        // write finished panel (coalesced along i)
        for (int p = 0; p < 16; ++p) {
            int k = k0 + p;
            if (tid >= k) LTb[k * 256 + tid] = PCH(p, tid);
        }
        // trailing update: 2x2 microtile per thread, 16-deep register panel
        int ty = tid >> 4, tx = tid & 15;
        for (int i2 = k0 + 16 + 2 * ty; i2 < 256; i2 += 32) {
            double pa[16], pb[16];
#pragma unroll
            for (int p = 0; p < 16; ++p) { pa[p] = PCH(p, i2); pb[p] = PCH(p, i2 + 1); }
            for (int j2 = k0 + 16 + 2 * tx; j2 <= i2 + 1; j2 += 32) {
                double g00 = 0.0, g01 = 0.0, g10 = 0.0, g11 = 0.0;
#pragma unroll
                for (int p = 0; p < 16; ++p) {
                    double q0 = PCH(p, j2), q1 = PCH(p, j2 + 1);
                    g00 += pa[p] * q0; g01 += pa[p] * q1;
                    g10 += pb[p] * q0; g11 += pb[p] * q1;
                }
                if (j2 <= i2)     Gb[i2 * 256 + j2]           -= g00;
                if (j2 + 1 <= i2) Gb[i2 * 256 + j2 + 1]       -= g01;
                Gb[(i2 + 1) * 256 + j2] -= g10;               // j2 <= i2+1 by loop bound
                if (j2 <= i2)     Gb[(i2 + 1) * 256 + j2 + 1] -= g11;
            }
        }
        __syncthreads();
    }
#undef PCH

    // ---------------- phase 2: trinv (SHD = S) ----------------
    double* SHD = S;   // 8 diag blocks: SHD[g*1024 + k*32 + i] = L[32g+i][32g+k]
    for (int idx = tid; idx < 65536; idx += 256) {
        int i = idx >> 8, k = idx & 255;
        if (k > i) { TIb[idx] = 0.0; TIFb[idx] = 0.0f; }
    }
    for (int idx = tid; idx < 8192; idx += 256) {
        int g = idx >> 10, rem = idx & 1023, k = rem >> 5, i = rem & 31;
        SHD[idx] = LTb[(32 * g + k) * 256 + 32 * g + i];
    }
    __syncthreads();
    {
        int g = tid >> 5, j = tid & 31;
        const double* D = SHD + g * 1024;       // D[k*32+i] = L[i][k]
        double x[32];
#pragma unroll
        for (int i = 0; i < 32; ++i) {
            double s = (i == j) ? 1.0 : 0.0;
#pragma unroll
            for (int k = 0; k < i; ++k) {
                double lv = D[k * 32 + i];
                s -= (k >= j) ? lv * x[k] : 0.0;
            }
            double inv = 1.0 / D[i * 32 + i];
            x[i] = (i >= j) ? s * inv : 0.0;
        }
#pragma unroll
        for (int i = 0; i < 32; ++i) {
            int gi = 32 * g + i, gj = 32 * g + j;
            TIb[gi * 256 + gj] = x[i];
            TIFb[gi * 256 + gj] = (float)x[i];
        }
    }
    __syncthreads();
    double* Bsh = SHD;
    int j = tid & 31, ig = tid >> 5;
    for (int I = 1; I < 8; ++I) {
        for (int J = I - 1; J >= 0; --J) {
            double acc[4] = {0.0, 0.0, 0.0, 0.0};
            for (int K = J; K < I; ++K) {
                for (int kk = 0; kk < 32; ++kk) {
                    double tv = TIb[(32 * K + kk) * 256 + 32 * J + j];
#pragma unroll
                    for (int r = 0; r < 4; ++r) {
                        double lv = LTb[(32 * K + kk) * 256 + 32 * I + ig * 4 + r];
                        acc[r] += lv * tv;
                    }
                }
            }
            __syncthreads();
#pragma unroll
            for (int r = 0; r < 4; ++r) Bsh[(ig * 4 + r) * 32 + j] = acc[r];
            __syncthreads();
            double c[4] = {0.0, 0.0, 0.0, 0.0};
            for (int k = 0; k < 32; ++k) {
                double bv = Bsh[k * 32 + j];
#pragma unroll
                for (int r = 0; r < 4; ++r) {
                    double dv = TIb[(32 * I + ig * 4 + r) * 256 + 32 * I + k];
                    c[r] -= dv * bv;
                }
            }
#pragma unroll
            for (int r = 0; r < 4; ++r) {
                int gi = 32 * I + ig * 4 + r, gj = 32 * J + j;
                TIb[gi * 256 + gj] = c[r];
                TIFb[gi * 256 + gj] = (float)c[r];
            }
        }
        __syncthreads();
    }
}

// ---------------------------------------------------------------------------
// K4a: Z = Tinv @ RHS  (fp64 tiled GEMM, triangular k-skip)
// ---------------------------------------------------------------------------
__global__ __launch_bounds__(256) void k_gemm_Z(const double* __restrict__ TI,
                                                const double* __restrict__ RHS,
                                                double* __restrict__ Z) {
    __shared__ double As[32][64];
    __shared__ double Bs[64][64];
    int b = blockIdx.x, i0 = blockIdx.y * 32;
    int tid = threadIdx.x, c = tid & 63, rg = tid >> 6;
    const double* TIb = TI + b * 65536;
    const double* Rb = RHS + b * 16384;
    double* Zb = Z + b * 16384;
    double acc[8] = {};
    for (int k0 = 0; k0 <= i0; k0 += 64) {
        for (int idx = tid; idx < 2048; idx += 256) {
            int r = idx >> 6, kk = idx & 63;
            As[r][kk] = TIb[(i0 + r) * 256 + k0 + kk];
        }
        for (int idx = tid; idx < 4096; idx += 256) {
            int kk = idx >> 6, cc = idx & 63;
            Bs[kk][cc] = Rb[(k0 + kk) * 64 + cc];
        }
        __syncthreads();
        for (int kk = 0; kk < 64; ++kk) {
            double bv = Bs[kk][c];
#pragma unroll
            for (int r = 0; r < 8; ++r)
                acc[r] += As[rg * 8 + r][kk] * bv;
        }
        __syncthreads();
    }
#pragma unroll
    for (int r = 0; r < 8; ++r)
        Zb[(i0 + rg * 8 + r) * 64 + c] = acc[r];
}

// ---------------------------------------------------------------------------
// K4b: M = Tinv^T @ Z  (fp64 tiled GEMM, triangular k-skip), M -> RHS buffer
// ---------------------------------------------------------------------------
__global__ __launch_bounds__(256) void k_gemm_M(const double* __restrict__ TI,
                                                const double* __restrict__ Z,
                                                double* __restrict__ M) {
    __shared__ double As[64][32];
    __shared__ double Bs[64][64];
    int b = blockIdx.x, i0 = blockIdx.y * 32;
    int tid = threadIdx.x, c = tid & 63, rg = tid >> 6;
    const double* TIb = TI + b * 65536;
    const double* Zb = Z + b * 16384;
    double* Mb = M + b * 16384;
    double acc[8] = {};
    for (int k0 = (i0 >> 6) << 6; k0 < 256; k0 += 64) {
        for (int idx = tid; idx < 2048; idx += 256) {
            int kk = idx >> 5, ri = idx & 31;
            As[kk][ri] = TIb[(k0 + kk) * 256 + i0 + ri];
        }
        for (int idx = tid; idx < 4096; idx += 256) {
            int kk = idx >> 6, cc = idx & 63;
            Bs[kk][cc] = Zb[(k0 + kk) * 64 + cc];
        }
        __syncthreads();
        for (int kk = 0; kk < 64; ++kk) {
            double bv = Bs[kk][c];
#pragma unroll
            for (int r = 0; r < 8; ++r)
                acc[r] += As[kk][rg * 8 + r] * bv;
        }
        __syncthreads();
    }
#pragma unroll
    for (int r = 0; r < 8; ++r)
        Mb[(i0 + rg * 8 + r) * 64 + c] = acc[r];
}

// ---------------------------------------------------------------------------
// K5: W = PhiQ @ TinvF^T, PSUM[b][I][q] = sum_{i in I-tile} W[q][i]^2 (fp32)
//     R2-proven layout (conflict-free staging, scalar A reads).
// ---------------------------------------------------------------------------
__global__ __launch_bounds__(256) void k_spread_gemm(const float* __restrict__ PHIQ,
                                                     const float* __restrict__ TIF,
                                                     float* __restrict__ PSUM) {
    __shared__ float Qs[64][65];   // [q][k]
    __shared__ float Ts[64][65];   // [k][i]
    int b = blockIdx.x, q0 = blockIdx.y * 64, I = blockIdx.z, i0 = I * 64;
    int tid = threadIdx.x, tx = tid & 15, ty = tid >> 4;
    const float* Qb = PHIQ + b * (NQ * DIN) + q0 * DIN;
    const float* Tb = TIF + b * 65536;
    float acc[4][4];
#pragma unroll
    for (int r = 0; r < 4; ++r)
#pragma unroll
        for (int s = 0; s < 4; ++s) acc[r][s] = 0.0f;
    for (int k0 = 0; k0 <= i0; k0 += 64) {
        for (int idx = tid; idx < 4096; idx += 256) {
            int r = idx >> 6, c = idx & 63;
            Qs[r][c] = Qb[r * 256 + k0 + c];
            Ts[c][r] = Tb[(i0 + r) * 256 + k0 + c];
        }
        __syncthreads();
        for (int kk = 0; kk < 64; ++kk) {
            float a0 = Qs[4 * ty + 0][kk], a1 = Qs[4 * ty + 1][kk];
            float a2 = Qs[4 * ty + 2][kk], a3 = Qs[4 * ty + 3][kk];
            float b0 = Ts[kk][4 * tx + 0], b1 = Ts[kk][4 * tx + 1];
            float b2 = Ts[kk][4 * tx + 2], b3 = Ts[kk][4 * tx + 3];
            acc[0][0] += a0 * b0; acc[0][1] += a0 * b1; acc[0][2] += a0 * b2; acc[0][3] += a0 * b3;
            acc[1][0] += a1 * b0; acc[1][1] += a1 * b1; acc[1][2] += a1 * b2; acc[1][3] += a1 * b3;
            acc[2][0] += a2 * b0; acc[2][1] += a2 * b1; acc[2][2] += a2 * b2; acc[2][3] += a2 * b3;
            acc[3][0] += a3 * b0; acc[3][1] += a3 * b1; acc[3][2] += a3 * b2; acc[3][3] += a3 * b3;
        }
        __syncthreads();
    }
#pragma unroll
    for (int r = 0; r < 4; ++r) {
        float p = acc[r][0] * acc[r][0] + acc[r][1] * acc[r][1]
                + acc[r][2] * acc[r][2] + acc[r][3] * acc[r][3];
        p += __shfl_down(p, 8, 16);
        p += __shfl_down(p, 4, 16);
        p += __shfl_down(p, 2, 16);
        p += __shfl_down(p, 1, 16);
        if (tx == 0) PSUM[(size_t)(b * 4 + I) * 512 + q0 + 4 * ty + r] = p;
    }
}

// ---------------------------------------------------------------------------
// K6: mu = Phi_q @ m (fp32), FUSED epilogue: spread combine -> SPREAD,
//     nll partial (resid^2, logs) -> one fp64 atomicAdd per block.
// ---------------------------------------------------------------------------
__global__ __launch_bounds__(256) void k_mu_nll(const float* __restrict__ PHIQ,
                                                const double* __restrict__ M,
                                                const float* __restrict__ YQ,
                                                const float* __restrict__ PSUM,
                                                const float* __restrict__ SE,
                                                float* __restrict__ SPREAD,
                                                double* __restrict__ NLLACC,
                                                float* __restrict__ MU) {
    __shared__ float Qs[64][65];
    __shared__ float Ms[64][64];
    __shared__ double nred[64];
    int b = blockIdx.x, q0 = blockIdx.y * 64, tid = threadIdx.x;
    int tx = tid & 15, ty = tid >> 4;
    const float* Qb = PHIQ + b * (NQ * DIN) + q0 * DIN;
    const double* Mb = M + b * 16384;
    float acc[4][4];
#pragma unroll
    for (int r = 0; r < 4; ++r)
#pragma unroll
        for (int s = 0; s < 4; ++s) acc[r][s] = 0.0f;
    for (int c0 = 0; c0 < 256; c0 += 64) {
        for (int idx = tid; idx < 4096; idx += 256) {
            int r = idx >> 6, c = idx & 63;
            Qs[r][c] = Qb[r * 256 + c0 + c];
            Ms[r][c] = (float)Mb[(c0 + r) * 64 + c];
        }
        __syncthreads();
        for (int kk = 0; kk < 64; ++kk) {
            float a0 = Qs[4 * ty + 0][kk], a1 = Qs[4 * ty + 1][kk];
            float a2 = Qs[4 * ty + 2][kk], a3 = Qs[4 * ty + 3][kk];
            float b0 = Ms[kk][4 * tx + 0], b1 = Ms[kk][4 * tx + 1];
            float b2 = Ms[kk][4 * tx + 2], b3 = Ms[kk][4 * tx + 3];
            acc[0][0] += a0 * b0; acc[0][1] += a0 * b1; acc[0][2] += a0 * b2; acc[0][3] += a0 * b3;
            acc[1][0] += a1 * b0; acc[1][1] += a1 * b1; acc[1][2] += a1 * b2; acc[1][3] += a1 * b3;
            acc[2][0] += a2 * b0; acc[2][1] += a2 * b1; acc[2][2] += a2 * b2; acc[2][3] += a2 * b3;
            acc[3][0] += a3 * b0; acc[3][1] += a3 * b1; acc[3][2] += a3 * b2; acc[3][3] += a3 * b3;
        }
        __syncthreads();
    }
    float se = SE[0];
#pragma unroll
    for (int r = 0; r < 4; ++r) {
        int q = q0 + 4 * ty + r;
        float4 v = make_float4(acc[r][0], acc[r][1], acc[r][2], acc[r][3]);
        *(float4*)&MU[(b * NQ + q) * 64 + 4 * tx] = v;
        // nll partial for this row
        float4 y = *(const float4*)&YQ[(size_t)(b * NQ + q) * 64 + 4 * tx];
        float dx = y.x - v.x, dy = y.y - v.y, dz = y.z - v.z, dw = y.w - v.w;
        float qs = dx * dx + dy * dy + dz * dz + dw * dw;
        qs += __shfl_down(qs, 8, 16);
        qs += __shfl_down(qs, 4, 16);
        qs += __shfl_down(qs, 2, 16);
        qs += __shfl_down(qs, 1, 16);
        if (tx == 0) {
            float sp = 1.0f + PSUM[(size_t)(b * 4 + 0) * 512 + q]
                            + PSUM[(size_t)(b * 4 + 1) * 512 + q]
                            + PSUM[(size_t)(b * 4 + 2) * 512 + q]
                            + PSUM[(size_t)(b * 4 + 3) * 512 + q];
            SPREAD[b * 512 + q] = sp;
            float val = 64.0f * (logf(sp) + logf(se)) + qs / (sp * se);
            nred[ty * 4 + r] = (double)val;
        }
    }
    __syncthreads();
    for (int s = 32; s > 0; s >>= 1) {
        if (tid < s) nred[tid] += nred[tid + s];
        __syncthreads();
    }
    if (tid == 0) atomicAdd(NLLACC, nred[0] * (1.0 / 65536.0));
}

// ---------------------------------------------------------------------------
// K6b: write nll scalar
// ---------------------------------------------------------------------------
__global__ void k_nll_final(const double* __restrict__ NLLACC,
                            float* __restrict__ out) {
    if (threadIdx.x == 0) out[NLL_IDX] = (float)NLLACC[0];
}

// ---------------------------------------------------------------------------
// K7 (runs LAST): stream sig; fully overwrites scratch inside d_out sig region.
// ---------------------------------------------------------------------------
__global__ __launch_bounds__(256) void k_sig(const float* __restrict__ SPREAD,
                                             const float* __restrict__ SE,
                                             float* __restrict__ out) {
    __shared__ float sv_s;
    int bq = blockIdx.x, tid = threadIdx.x;
    if (tid == 0) sv_s = SPREAD[bq] * SE[0];
    __syncthreads();
    float sv = sv_s;
    float* base = out + (size_t)MU_SIZE + (size_t)bq * 4096;
    int i = tid >> 2;
    int jb = (tid & 3) << 4;
    int d = i - jb;
    float vals[16];
#pragma unroll
    for (int t = 0; t < 16; ++t) vals[t] = (t == d) ? sv : 0.0f;
    float4* p = (float4*)(base + tid * 16);
    p[0] = make_float4(vals[0], vals[1], vals[2], vals[3]);
    p[1] = make_float4(vals[4], vals[5], vals[6], vals[7]);
    p[2] = make_float4(vals[8], vals[9], vals[10], vals[11]);
    p[3] = make_float4(vals[12], vals[13], vals[14], vals[15]);
}

// ---------------------------------------------------------------------------
extern "C" void kernel_launch(void* const* d_in, const int* in_sizes, int n_in,
                              void* d_out, int out_size, void* d_ws, size_t ws_size,
                              hipStream_t stream) {
    const float* PHI_S = (const float*)d_in[0];
    const float* Y_S   = (const float*)d_in[1];
    const float* PHI_Q = (const float*)d_in[2];
    const float* Y_Q   = (const float*)d_in[3];
    const float* MP    = (const float*)d_in[4];
    const float* AP    = (const float*)d_in[5];
    const float* SE    = (const float*)d_in[6];
    float* out = (float*)d_out;

    // Big scratch inside sig region of d_out (dead before k_sig runs last).
    double* scratch = (double*)(out + MU_SIZE);
    double* G    = scratch;                    // 8,388,608 dbl (64 MB)
    double* LT   = G + 8388608;                // 8,388,608 dbl
    double* RHS  = LT + 8388608;               // 2,097,152 dbl (-> becomes M)
    double* Z    = RHS + 2097152;              // 2,097,152 dbl
    double* TI   = Z + 2097152;                // 8,388,608 dbl
    double* Spd  = TI + 8388608;               // 65,536 dbl
    double* MPN  = Spd + 65536;                // 16,384 dbl
    float*  TIF  = (float*)(MPN + 16384);      // 8,388,608 f32 (32 MB)
    float*  PSUM = TIF + 8388608;              // 262,144 f32 (1 MB)
    // Small persistent scratch (survives until k_sig) in d_ws (proven 258 KB).
    float*  SPREAD = (float*)d_ws;                        // 65,536 f32
    double* NLLACC = (double*)((char*)d_ws + 65536 * 4);  // 1 dbl

    k_prior_sp   <<<256, 256, 0, stream>>>(AP, Spd, NLLACC);
    k_prior_mpn  <<<256, 64, 0, stream>>>(Spd, MP, MPN);
    k_build_G    <<<dim3(B_T, 10), 256, 0, stream>>>(PHI_S, Spd, G);
    k_build_rhs  <<<dim3(B_T, 4), 256, 0, stream>>>(PHI_S, Y_S, MPN, RHS);
    k_cholinv    <<<B_T, 256, 0, stream>>>(G, LT, TI, TIF);
    k_gemm_Z     <<<dim3(B_T, 8), 256, 0, stream>>>(TI, RHS, Z);
    k_gemm_M     <<<dim3(B_T, 8), 256, 0, stream>>>(TI, Z, RHS);
    k_spread_gemm<<<dim3(B_T, 8, 4), 256, 0, stream>>>(PHI_Q, TIF, PSUM);
    k_mu_nll     <<<dim3(B_T, 8), 256, 0, stream>>>(PHI_Q, RHS, Y_Q, PSUM, SE,
                                                    SPREAD, NLLACC, out);
    k_nll_final  <<<1, 64, 0, stream>>>(NLLACC, out);
    k_sig        <<<65536, 256, 0, stream>>>(SPREAD, SE, out);   // LAST
}